// Round 2
// baseline (2660.522 us; speedup 1.0000x reference)
//
#include <hip/hip_runtime.h>
#include <hip/hip_bf16.h>

#define N_NODES_C 100000
#define IN_DIM 256
#define HID 128
#define BN_EPS 1e-5f

// ---------------- CSR build ----------------

__global__ void count_deg_kernel(const int* __restrict__ ei, int* __restrict__ deg, int E) {
    int e = blockIdx.x * blockDim.x + threadIdx.x;
    if (e < E) atomicAdd(&deg[ei[E + e]], 1);
}

#define SCAN_THREADS 256
#define SCAN_ELEMS 1024

__global__ __launch_bounds__(SCAN_THREADS) void scan1_kernel(const int* __restrict__ deg,
                                                             int* __restrict__ outp,
                                                             int* __restrict__ bsum, int n) {
    __shared__ int sdata[SCAN_THREADS];
    int t = threadIdx.x;
    int base = blockIdx.x * SCAN_ELEMS + t * 4;
    int v0 = 0, v1 = 0, v2 = 0, v3 = 0;
    if (base + 0 < n) v0 = deg[base + 0];
    if (base + 1 < n) v1 = deg[base + 1];
    if (base + 2 < n) v2 = deg[base + 2];
    if (base + 3 < n) v3 = deg[base + 3];
    int s = v0 + v1 + v2 + v3;
    sdata[t] = s;
    __syncthreads();
    int val = s;
    for (int off = 1; off < SCAN_THREADS; off <<= 1) {
        int add = (t >= off) ? sdata[t - off] : 0;
        __syncthreads();
        val += add;
        sdata[t] = val;
        __syncthreads();
    }
    int excl = val - s;
    if (base + 0 < n) outp[base + 0] = excl;
    if (base + 1 < n) outp[base + 1] = excl + v0;
    if (base + 2 < n) outp[base + 2] = excl + v0 + v1;
    if (base + 3 < n) outp[base + 3] = excl + v0 + v1 + v2;
    if (t == SCAN_THREADS - 1) bsum[blockIdx.x] = val;
}

__global__ void scan2_kernel(int* bsum, int nb) {
    if (threadIdx.x == 0 && blockIdx.x == 0) {
        int acc = 0;
        for (int i = 0; i < nb; i++) { int v = bsum[i]; bsum[i] = acc; acc += v; }
        bsum[nb] = acc;
    }
}

__global__ void scan3_kernel(int* __restrict__ row_ptr, const int* __restrict__ bsum, int n, int nb) {
    int i = blockIdx.x * blockDim.x + threadIdx.x;
    if (i < n) row_ptr[i] += bsum[i >> 10];
    else if (i == n) row_ptr[n] = bsum[nb];
}

__global__ void fill_csr_kernel(const int* __restrict__ ei, int* __restrict__ cursor,
                                int* __restrict__ esrc, int E) {
    int e = blockIdx.x * blockDim.x + threadIdx.x;
    if (e < E) {
        int s = ei[e];
        int d = ei[E + e];
        int pos = atomicAdd(&cursor[d], 1);
        esrc[pos] = s;
    }
}

// ---------------- Aggregation: mean over in-neighbors ----------------
// one wave per node, lane owns 2 columns (float2); neighbor row reads are
// 512B coalesced wave loads from L3-resident h.

__global__ __launch_bounds__(256) void sage_mean_kernel(const float* __restrict__ h,
                                                        const int* __restrict__ row_ptr,
                                                        const int* __restrict__ esrc,
                                                        float* __restrict__ meanb, int n) {
    int node = blockIdx.x * 4 + (threadIdx.x >> 6);
    if (node >= n) return;
    int lane = threadIdx.x & 63;
    int start = row_ptr[node];
    int end = row_ptr[node + 1];
    float ax = 0.f, ay = 0.f;
    for (int j = start; j < end; ++j) {
        int s = esrc[j];
        const float2 v = *(const float2*)(h + (size_t)s * HID + lane * 2);
        ax += v.x; ay += v.y;
    }
    int deg = end - start;
    float inv = 1.0f / (float)(deg > 1 ? deg : 1);
    float2 o; o.x = ax * inv; o.y = ay * inv;
    *(float2*)(meanb + (size_t)node * HID + lane * 2) = o;
}

// ---------------- Input GEMM: h = relu(x @ W_in + b_in) ----------------

__global__ __launch_bounds__(256) void input_gemm_kernel(const float* __restrict__ x,
                                                         const float* __restrict__ W,
                                                         const float* __restrict__ b,
                                                         float* __restrict__ h, int n) {
    __shared__ float Ws[IN_DIM * HID];  // 128 KB
    __shared__ float Xs[8][IN_DIM];     // 8 KB
    int t = threadIdx.x;
    for (int i = t * 4; i < IN_DIM * HID; i += 256 * 4) {
        *(float4*)&Ws[i] = *(const float4*)&W[i];
    }
    int c = t & 127;
    int rg = t >> 7;
    int r0 = rg * 4;
    float bc = b[c];
    int ntiles = (n + 7) >> 3;
    for (int tile = blockIdx.x; tile < ntiles; tile += gridDim.x) {
        int row0 = tile * 8;
        __syncthreads();
        for (int i = t * 4; i < 8 * IN_DIM; i += 1024) {
            int r = i >> 8;
            int k = i & 255;
            int row = row0 + r;
            float4 v = {0.f, 0.f, 0.f, 0.f};
            if (row < n) v = *(const float4*)&x[(size_t)row * IN_DIM + k];
            *(float4*)&Xs[r][k] = v;
        }
        __syncthreads();
        float acc0 = 0.f, acc1 = 0.f, acc2 = 0.f, acc3 = 0.f;
        #pragma unroll 8
        for (int k = 0; k < IN_DIM; k += 4) {
            float w0 = Ws[(k + 0) * HID + c];
            float w1 = Ws[(k + 1) * HID + c];
            float w2 = Ws[(k + 2) * HID + c];
            float w3 = Ws[(k + 3) * HID + c];
            float4 x0 = *(const float4*)&Xs[r0 + 0][k];
            float4 x1 = *(const float4*)&Xs[r0 + 1][k];
            float4 x2 = *(const float4*)&Xs[r0 + 2][k];
            float4 x3 = *(const float4*)&Xs[r0 + 3][k];
            acc0 += x0.x * w0 + x0.y * w1 + x0.z * w2 + x0.w * w3;
            acc1 += x1.x * w0 + x1.y * w1 + x1.z * w2 + x1.w * w3;
            acc2 += x2.x * w0 + x2.y * w1 + x2.z * w2 + x2.w * w3;
            acc3 += x3.x * w0 + x3.y * w1 + x3.z * w2 + x3.w * w3;
        }
        float accs[4] = {acc0, acc1, acc2, acc3};
        #pragma unroll
        for (int r = 0; r < 4; r++) {
            int row = row0 + r0 + r;
            if (row < n) {
                float z = accs[r] + bc;
                h[(size_t)row * HID + c] = z > 0.f ? z : 0.f;
            }
        }
    }
}

// ---------------- Fused SAGE layer ----------------
// h_new = relu( BN( mean@Wl + h@Wr + bl + br ) ) + h_in ; writes over mean buffer.

__global__ __launch_bounds__(256) void sage_layer_kernel(const float* __restrict__ h,
                                                         float* __restrict__ mh,
                                                         const float* __restrict__ Wl,
                                                         const float* __restrict__ bl,
                                                         const float* __restrict__ Wr,
                                                         const float* __restrict__ br,
                                                         const float* __restrict__ gamma,
                                                         const float* __restrict__ beta,
                                                         const float* __restrict__ bmean,
                                                         const float* __restrict__ bvar,
                                                         int n) {
    __shared__ float Wls[HID * HID];  // 64 KB
    __shared__ float Wrs[HID * HID];  // 64 KB
    __shared__ float Ms[8][HID];      // 4 KB
    __shared__ float Hs[8][HID];      // 4 KB
    int t = threadIdx.x;
    for (int i = t * 4; i < HID * HID; i += 1024) {
        *(float4*)&Wls[i] = *(const float4*)&Wl[i];
        *(float4*)&Wrs[i] = *(const float4*)&Wr[i];
    }
    int c = t & 127;
    int rg = t >> 7;
    int r0 = rg * 4;
    float scale = gamma[c] * rsqrtf(bvar[c] + BN_EPS);
    float shift = beta[c] - bmean[c] * scale + (bl[c] + br[c]) * scale;
    int ntiles = (n + 7) >> 3;
    for (int tile = blockIdx.x; tile < ntiles; tile += gridDim.x) {
        int row0 = tile * 8;
        __syncthreads();
        {
            // 256 threads x float4 = 1024 floats = exactly one 8x128 tile per buffer
            int i = t * 4;
            int r = i >> 7;
            int k = i & 127;
            int row = row0 + r;
            float4 vm = {0.f, 0.f, 0.f, 0.f};
            float4 vh = {0.f, 0.f, 0.f, 0.f};
            if (row < n) {
                vm = *(const float4*)&mh[(size_t)row * HID + k];
                vh = *(const float4*)&h[(size_t)row * HID + k];
            }
            *(float4*)&Ms[r][k] = vm;
            *(float4*)&Hs[r][k] = vh;
        }
        __syncthreads();
        float acc[4] = {0.f, 0.f, 0.f, 0.f};
        #pragma unroll 8
        for (int k = 0; k < HID; k += 4) {
            float wl0 = Wls[(k + 0) * HID + c];
            float wl1 = Wls[(k + 1) * HID + c];
            float wl2 = Wls[(k + 2) * HID + c];
            float wl3 = Wls[(k + 3) * HID + c];
            float wr0 = Wrs[(k + 0) * HID + c];
            float wr1 = Wrs[(k + 1) * HID + c];
            float wr2 = Wrs[(k + 2) * HID + c];
            float wr3 = Wrs[(k + 3) * HID + c];
            #pragma unroll
            for (int r = 0; r < 4; r++) {
                float4 m = *(const float4*)&Ms[r0 + r][k];
                float4 hh = *(const float4*)&Hs[r0 + r][k];
                acc[r] += m.x * wl0 + m.y * wl1 + m.z * wl2 + m.w * wl3
                        + hh.x * wr0 + hh.y * wr1 + hh.z * wr2 + hh.w * wr3;
            }
        }
        #pragma unroll
        for (int r = 0; r < 4; r++) {
            int row = row0 + r0 + r;
            if (row < n) {
                float z = acc[r] * scale + shift;
                z = z > 0.f ? z : 0.f;
                mh[(size_t)row * HID + c] = z + Hs[r0 + r][c];
            }
        }
    }
}

// ---------------- Classifier + log_softmax ----------------

__global__ __launch_bounds__(256) void classifier_kernel(const float* __restrict__ h,
                                                         const float* __restrict__ Wc,
                                                         const float* __restrict__ bc,
                                                         float* __restrict__ outp, int n) {
    __shared__ float Wcs[HID * 2];
    int t = threadIdx.x;
    if (t < 64) *(float4*)&Wcs[t * 4] = *(const float4*)&Wc[t * 4];
    __syncthreads();
    int rowInBlk = t >> 4;
    int sub = t & 15;
    int row = blockIdx.x * 16 + rowInBlk;
    float l0 = 0.f, l1 = 0.f;
    if (row < n) {
        const float* hr = h + (size_t)row * HID + sub * 8;
        float4 a = *(const float4*)hr;
        float4 b2 = *(const float4*)(hr + 4);
        int k0 = sub * 8;
        l0 += a.x * Wcs[(k0 + 0) * 2] + a.y * Wcs[(k0 + 1) * 2] + a.z * Wcs[(k0 + 2) * 2] + a.w * Wcs[(k0 + 3) * 2];
        l1 += a.x * Wcs[(k0 + 0) * 2 + 1] + a.y * Wcs[(k0 + 1) * 2 + 1] + a.z * Wcs[(k0 + 2) * 2 + 1] + a.w * Wcs[(k0 + 3) * 2 + 1];
        l0 += b2.x * Wcs[(k0 + 4) * 2] + b2.y * Wcs[(k0 + 5) * 2] + b2.z * Wcs[(k0 + 6) * 2] + b2.w * Wcs[(k0 + 7) * 2];
        l1 += b2.x * Wcs[(k0 + 4) * 2 + 1] + b2.y * Wcs[(k0 + 5) * 2 + 1] + b2.z * Wcs[(k0 + 6) * 2 + 1] + b2.w * Wcs[(k0 + 7) * 2 + 1];
    }
    #pragma unroll
    for (int off = 1; off < 16; off <<= 1) {
        l0 += __shfl_xor(l0, off);
        l1 += __shfl_xor(l1, off);
    }
    if (sub == 0 && row < n) {
        l0 += bc[0];
        l1 += bc[1];
        float m = fmaxf(l0, l1);
        float lse = m + logf(expf(l0 - m) + expf(l1 - m));
        outp[(size_t)row * 2 + 0] = l0 - lse;
        outp[(size_t)row * 2 + 1] = l1 - lse;
    }
}

// ---------------- host ----------------

extern "C" void kernel_launch(void* const* d_in, const int* in_sizes, int n_in,
                              void* d_out, int out_size, void* d_ws, size_t ws_size,
                              hipStream_t stream) {
    const float* x     = (const float*)d_in[0];
    const int*   ei    = (const int*)d_in[1];
    const float* W_in  = (const float*)d_in[2];
    const float* b_in  = (const float*)d_in[3];
    const float* W_l   = (const float*)d_in[4];
    const float* b_l   = (const float*)d_in[5];
    const float* W_r   = (const float*)d_in[6];
    const float* b_r   = (const float*)d_in[7];
    const float* bn_g  = (const float*)d_in[8];
    const float* bn_b  = (const float*)d_in[9];
    const float* bn_m  = (const float*)d_in[10];
    const float* bn_v  = (const float*)d_in[11];
    const float* W_cls = (const float*)d_in[12];
    const float* b_cls = (const float*)d_in[13];
    float* outp = (float*)d_out;

    const int N = in_sizes[0] / IN_DIM;   // 100000
    const int E = in_sizes[1] / 2;        // 1600000

    char* w = (char*)d_ws;
    const size_t HBYTES = (size_t)N * HID * sizeof(float);      // 51.2 MB
    float* hA      = (float*)(w);
    float* hB      = (float*)(w + HBYTES);
    int*   row_ptr = (int*)(w + 2 * HBYTES);                    // N+1 ints
    int*   cursor  = (int*)(w + 2 * HBYTES + 400128);           // N ints (also deg temp)
    int*   bsum    = (int*)(w + 2 * HBYTES + 800256);           // scan block sums
    int*   esrc    = (int*)(w + 2 * HBYTES + 801280);           // E ints

    const int nbScan = (N + SCAN_ELEMS - 1) / SCAN_ELEMS;       // 98

    // --- CSR build ---
    hipMemsetAsync(cursor, 0, (size_t)N * sizeof(int), stream);
    count_deg_kernel<<<(E + 255) / 256, 256, 0, stream>>>(ei, cursor, E);
    scan1_kernel<<<nbScan, SCAN_THREADS, 0, stream>>>(cursor, row_ptr, bsum, N);
    scan2_kernel<<<1, 64, 0, stream>>>(bsum, nbScan);
    scan3_kernel<<<(N + 256) / 256, 256, 0, stream>>>(row_ptr, bsum, N, nbScan);
    hipMemcpyAsync(cursor, row_ptr, (size_t)N * sizeof(int), hipMemcpyDeviceToDevice, stream);
    fill_csr_kernel<<<(E + 255) / 256, 256, 0, stream>>>(ei, cursor, esrc, E);

    // --- input projection ---
    input_gemm_kernel<<<512, 256, 0, stream>>>(x, W_in, b_in, hA, N);

    // --- 4 SAGE layers ---
    float* hcur = hA;
    float* hoth = hB;
    for (int i = 0; i < 4; i++) {
        sage_mean_kernel<<<(N + 3) / 4, 256, 0, stream>>>(hcur, row_ptr, esrc, hoth, N);
        sage_layer_kernel<<<512, 256, 0, stream>>>(hcur, hoth,
                                                   W_l + (size_t)i * HID * HID, b_l + i * HID,
                                                   W_r + (size_t)i * HID * HID, b_r + i * HID,
                                                   bn_g + i * HID, bn_b + i * HID,
                                                   bn_m + i * HID, bn_v + i * HID, N);
        float* tmp = hcur; hcur = hoth; hoth = tmp;
    }

    // --- classifier + log_softmax ---
    classifier_kernel<<<(N + 15) / 16, 256, 0, stream>>>(hcur, W_cls, b_cls, outp, N);
}

// Round 3
// 827.193 us; speedup vs baseline: 3.2163x; 3.2163x over previous
//
#include <hip/hip_runtime.h>

typedef unsigned int uint;
typedef unsigned short ushort;
typedef __attribute__((ext_vector_type(8))) short short8v;  // 8 bf16 bit patterns
typedef __attribute__((ext_vector_type(4))) float f32x4;

#define IN_DIM 256
#define HID 128
#define BN_EPS 1e-5f

__device__ __forceinline__ float bf2f(ushort u) { return __uint_as_float(((uint)u) << 16); }
__device__ __forceinline__ ushort f2bf(float f) {
    uint u = __float_as_uint(f);
    return (ushort)((u + 0x7fffu + ((u >> 16) & 1u)) >> 16);  // RNE
}

// ---------------- CSR build ----------------

__global__ void count_deg_kernel(const int* __restrict__ ei, int* __restrict__ deg, int E) {
    int e = blockIdx.x * blockDim.x + threadIdx.x;
    if (e < E) atomicAdd(&deg[ei[E + e]], 1);
}

#define SCAN_THREADS 256
#define SCAN_ELEMS 1024

__global__ __launch_bounds__(SCAN_THREADS) void scan1_kernel(const int* __restrict__ deg,
                                                             int* __restrict__ outp,
                                                             int* __restrict__ bsum, int n) {
    __shared__ int sdata[SCAN_THREADS];
    int t = threadIdx.x;
    int base = blockIdx.x * SCAN_ELEMS + t * 4;
    int v0 = 0, v1 = 0, v2 = 0, v3 = 0;
    if (base + 0 < n) v0 = deg[base + 0];
    if (base + 1 < n) v1 = deg[base + 1];
    if (base + 2 < n) v2 = deg[base + 2];
    if (base + 3 < n) v3 = deg[base + 3];
    int s = v0 + v1 + v2 + v3;
    sdata[t] = s;
    __syncthreads();
    int val = s;
    for (int off = 1; off < SCAN_THREADS; off <<= 1) {
        int add = (t >= off) ? sdata[t - off] : 0;
        __syncthreads();
        val += add;
        sdata[t] = val;
        __syncthreads();
    }
    int excl = val - s;
    if (base + 0 < n) outp[base + 0] = excl;
    if (base + 1 < n) outp[base + 1] = excl + v0;
    if (base + 2 < n) outp[base + 2] = excl + v0 + v1;
    if (base + 3 < n) outp[base + 3] = excl + v0 + v1 + v2;
    if (t == SCAN_THREADS - 1) bsum[blockIdx.x] = val;
}

__global__ void scan2_kernel(int* bsum, int nb) {
    if (threadIdx.x == 0 && blockIdx.x == 0) {
        int acc = 0;
        for (int i = 0; i < nb; i++) { int v = bsum[i]; bsum[i] = acc; acc += v; }
        bsum[nb] = acc;
    }
}

__global__ void scan3_kernel(int* __restrict__ row_ptr, const int* __restrict__ bsum, int n, int nb) {
    int i = blockIdx.x * blockDim.x + threadIdx.x;
    if (i < n) row_ptr[i] += bsum[i >> 10];
    else if (i == n) row_ptr[n] = bsum[nb];
}

__global__ void fill_csr_kernel(const int* __restrict__ ei, int* __restrict__ cursor,
                                int* __restrict__ esrc, int E) {
    int e = blockIdx.x * blockDim.x + threadIdx.x;
    if (e < E) {
        int s = ei[e];
        int d = ei[E + e];
        int pos = atomicAdd(&cursor[d], 1);
        esrc[pos] = s;
    }
}

// ---------------- Aggregation: mean over in-neighbors (bf16 rows) ----------------
// one wave per node; lane owns 2 cols (one dword = 2 bf16); per edge = one
// 256B fully-coalesced wave load. fp32 accumulate, bf16 out.

__global__ __launch_bounds__(256) void sage_mean_bf16(const ushort* __restrict__ h,
                                                      const int* __restrict__ row_ptr,
                                                      const int* __restrict__ esrc,
                                                      ushort* __restrict__ meanb, int n) {
    int node = blockIdx.x * 4 + (threadIdx.x >> 6);
    if (node >= n) return;
    int lane = threadIdx.x & 63;
    int start = row_ptr[node];
    int end = row_ptr[node + 1];
    float ax = 0.f, ay = 0.f;
    int j = start;
    for (; j + 1 < end; j += 2) {
        int s0 = esrc[j];
        int s1 = esrc[j + 1];
        uint v0 = *(const uint*)(h + (size_t)s0 * HID + lane * 2);
        uint v1 = *(const uint*)(h + (size_t)s1 * HID + lane * 2);
        ax += bf2f((ushort)(v0 & 0xffffu)) + bf2f((ushort)(v1 & 0xffffu));
        ay += bf2f((ushort)(v0 >> 16)) + bf2f((ushort)(v1 >> 16));
    }
    if (j < end) {
        int s0 = esrc[j];
        uint v0 = *(const uint*)(h + (size_t)s0 * HID + lane * 2);
        ax += bf2f((ushort)(v0 & 0xffffu));
        ay += bf2f((ushort)(v0 >> 16));
    }
    int deg = end - start;
    float inv = 1.0f / (float)(deg > 1 ? deg : 1);
    uint o = (uint)f2bf(ax * inv) | (((uint)f2bf(ay * inv)) << 16);
    *(uint*)(meanb + (size_t)node * HID + lane * 2) = o;
}

// ---------------- Input GEMM: h = relu(x @ W_in + b_in), MFMA ----------------
// block = 4 waves; M-tile 16 rows; wave owns 32 cols (2 N-tiles).
// B (weights) in registers, gathered once per block. No LDS.

__global__ __launch_bounds__(256) void input_gemm_mfma(const float* __restrict__ x,
                                                       const float* __restrict__ W,
                                                       const float* __restrict__ b,
                                                       ushort* __restrict__ hout, int n) {
    int t = threadIdx.x;
    int l = t & 63;
    int wv = t >> 6;
    int colbase = wv * 32;
    int lr = l & 15;   // A-row / B,D-col within tile
    int grp = l >> 4;  // k-group
    int ko = grp * 8;

    short8v Bf[8][2];
    #pragma unroll
    for (int ks = 0; ks < 8; ks++) {
        #pragma unroll
        for (int nt = 0; nt < 2; nt++) {
            int c = colbase + nt * 16 + lr;
            short8v f;
            #pragma unroll
            for (int jj = 0; jj < 8; jj++)
                f[jj] = (short)f2bf(W[(size_t)(ks * 32 + ko + jj) * HID + c]);
            Bf[ks][nt] = f;
        }
    }
    float bias0 = b[colbase + lr];
    float bias1 = b[colbase + 16 + lr];

    int ntiles = (n + 15) >> 4;
    for (int tile = blockIdx.x; tile < ntiles; tile += gridDim.x) {
        int row0 = tile * 16;
        int arow = row0 + lr;
        const float* xr = x + (size_t)arow * IN_DIM + ko;
        short8v Af[8];
        if (arow < n) {
            #pragma unroll
            for (int ks = 0; ks < 8; ks++) {
                float4 p = *(const float4*)(xr + ks * 32);
                float4 q = *(const float4*)(xr + ks * 32 + 4);
                short8v a;
                a[0] = (short)f2bf(p.x); a[1] = (short)f2bf(p.y);
                a[2] = (short)f2bf(p.z); a[3] = (short)f2bf(p.w);
                a[4] = (short)f2bf(q.x); a[5] = (short)f2bf(q.y);
                a[6] = (short)f2bf(q.z); a[7] = (short)f2bf(q.w);
                Af[ks] = a;
            }
        } else {
            #pragma unroll
            for (int ks = 0; ks < 8; ks++) {
                short8v a = {0, 0, 0, 0, 0, 0, 0, 0};
                Af[ks] = a;
            }
        }
        f32x4 acc0 = {0.f, 0.f, 0.f, 0.f};
        f32x4 acc1 = {0.f, 0.f, 0.f, 0.f};
        #pragma unroll
        for (int ks = 0; ks < 8; ks++) {
            acc0 = __builtin_amdgcn_mfma_f32_16x16x32_bf16(Af[ks], Bf[ks][0], acc0, 0, 0, 0);
            acc1 = __builtin_amdgcn_mfma_f32_16x16x32_bf16(Af[ks], Bf[ks][1], acc1, 0, 0, 0);
        }
        int rbase = row0 + grp * 4;
        #pragma unroll
        for (int r = 0; r < 4; r++) {
            int rowd = rbase + r;
            if (rowd < n) {
                float z0 = acc0[r] + bias0; z0 = z0 > 0.f ? z0 : 0.f;
                float z1 = acc1[r] + bias1; z1 = z1 > 0.f ? z1 : 0.f;
                hout[(size_t)rowd * HID + colbase + lr] = f2bf(z0);
                hout[(size_t)rowd * HID + colbase + 16 + lr] = f2bf(z1);
            }
        }
    }
}

// ---------------- Fused SAGE layer, MFMA ----------------
// hout = relu(BN(mean@Wl + h@Wr + biases)) + h ; K=256 over concat[mean|h].

__global__ __launch_bounds__(256) void sage_layer_mfma(const ushort* __restrict__ h,
                                                       const ushort* __restrict__ mh,
                                                       ushort* __restrict__ hout,
                                                       const float* __restrict__ Wl,
                                                       const float* __restrict__ bl,
                                                       const float* __restrict__ Wr,
                                                       const float* __restrict__ br,
                                                       const float* __restrict__ gamma,
                                                       const float* __restrict__ beta,
                                                       const float* __restrict__ bmean,
                                                       const float* __restrict__ bvar,
                                                       int n) {
    int t = threadIdx.x;
    int l = t & 63;
    int wv = t >> 6;
    int colbase = wv * 32;
    int lr = l & 15;
    int grp = l >> 4;
    int ko = grp * 8;

    short8v Bf[8][2];
    #pragma unroll
    for (int ks = 0; ks < 8; ks++) {
        const float* Wsrc = (ks < 4) ? Wl : Wr;
        int kb = (ks < 4) ? ks * 32 : (ks - 4) * 32;
        #pragma unroll
        for (int nt = 0; nt < 2; nt++) {
            int c = colbase + nt * 16 + lr;
            short8v f;
            #pragma unroll
            for (int jj = 0; jj < 8; jj++)
                f[jj] = (short)f2bf(Wsrc[(size_t)(kb + ko + jj) * HID + c]);
            Bf[ks][nt] = f;
        }
    }
    int c0 = colbase + lr;
    int c1 = c0 + 16;
    float scale0 = gamma[c0] * rsqrtf(bvar[c0] + BN_EPS);
    float scale1 = gamma[c1] * rsqrtf(bvar[c1] + BN_EPS);
    float shift0 = beta[c0] + (bl[c0] + br[c0] - bmean[c0]) * scale0;
    float shift1 = beta[c1] + (bl[c1] + br[c1] - bmean[c1]) * scale1;

    int ntiles = (n + 15) >> 4;
    for (int tile = blockIdx.x; tile < ntiles; tile += gridDim.x) {
        int row0 = tile * 16;
        int arow = row0 + lr;
        short8v Af[8];
        if (arow < n) {
            const ushort* mrow = mh + (size_t)arow * HID + ko;
            const ushort* hrow = h + (size_t)arow * HID + ko;
            #pragma unroll
            for (int ks = 0; ks < 4; ks++) Af[ks] = *(const short8v*)(mrow + ks * 32);
            #pragma unroll
            for (int ks = 4; ks < 8; ks++) Af[ks] = *(const short8v*)(hrow + (ks - 4) * 32);
        } else {
            #pragma unroll
            for (int ks = 0; ks < 8; ks++) {
                short8v a = {0, 0, 0, 0, 0, 0, 0, 0};
                Af[ks] = a;
            }
        }
        f32x4 acc0 = {0.f, 0.f, 0.f, 0.f};
        f32x4 acc1 = {0.f, 0.f, 0.f, 0.f};
        #pragma unroll
        for (int ks = 0; ks < 8; ks++) {
            acc0 = __builtin_amdgcn_mfma_f32_16x16x32_bf16(Af[ks], Bf[ks][0], acc0, 0, 0, 0);
            acc1 = __builtin_amdgcn_mfma_f32_16x16x32_bf16(Af[ks], Bf[ks][1], acc1, 0, 0, 0);
        }
        int rbase = row0 + grp * 4;
        #pragma unroll
        for (int r = 0; r < 4; r++) {
            int rowd = rbase + r;
            if (rowd < n) {
                float z0 = acc0[r] * scale0 + shift0; z0 = z0 > 0.f ? z0 : 0.f;
                float z1 = acc1[r] * scale1 + shift1; z1 = z1 > 0.f ? z1 : 0.f;
                z0 += bf2f(h[(size_t)rowd * HID + c0]);
                z1 += bf2f(h[(size_t)rowd * HID + c1]);
                hout[(size_t)rowd * HID + c0] = f2bf(z0);
                hout[(size_t)rowd * HID + c1] = f2bf(z1);
            }
        }
    }
}

// ---------------- Classifier + log_softmax (bf16 h) ----------------

__global__ __launch_bounds__(256) void classifier_bf16(const ushort* __restrict__ h,
                                                       const float* __restrict__ Wc,
                                                       const float* __restrict__ bc,
                                                       float* __restrict__ outp, int n) {
    __shared__ float Wcs[HID * 2];
    int t = threadIdx.x;
    if (t < 64) *(float4*)&Wcs[t * 4] = *(const float4*)&Wc[t * 4];
    __syncthreads();
    int rowInBlk = t >> 4;
    int sub = t & 15;
    int row = blockIdx.x * 16 + rowInBlk;
    float l0 = 0.f, l1 = 0.f;
    if (row < n) {
        const ushort* hr = h + (size_t)row * HID + sub * 8;
        uint4 v = *(const uint4*)hr;
        float e0 = bf2f((ushort)(v.x & 0xffffu)), e1 = bf2f((ushort)(v.x >> 16));
        float e2 = bf2f((ushort)(v.y & 0xffffu)), e3 = bf2f((ushort)(v.y >> 16));
        float e4 = bf2f((ushort)(v.z & 0xffffu)), e5 = bf2f((ushort)(v.z >> 16));
        float e6 = bf2f((ushort)(v.w & 0xffffu)), e7 = bf2f((ushort)(v.w >> 16));
        int k0 = sub * 8;
        l0 += e0 * Wcs[(k0 + 0) * 2] + e1 * Wcs[(k0 + 1) * 2] + e2 * Wcs[(k0 + 2) * 2] + e3 * Wcs[(k0 + 3) * 2];
        l0 += e4 * Wcs[(k0 + 4) * 2] + e5 * Wcs[(k0 + 5) * 2] + e6 * Wcs[(k0 + 6) * 2] + e7 * Wcs[(k0 + 7) * 2];
        l1 += e0 * Wcs[(k0 + 0) * 2 + 1] + e1 * Wcs[(k0 + 1) * 2 + 1] + e2 * Wcs[(k0 + 2) * 2 + 1] + e3 * Wcs[(k0 + 3) * 2 + 1];
        l1 += e4 * Wcs[(k0 + 4) * 2 + 1] + e5 * Wcs[(k0 + 5) * 2 + 1] + e6 * Wcs[(k0 + 6) * 2 + 1] + e7 * Wcs[(k0 + 7) * 2 + 1];
    }
    #pragma unroll
    for (int off = 1; off < 16; off <<= 1) {
        l0 += __shfl_xor(l0, off);
        l1 += __shfl_xor(l1, off);
    }
    if (sub == 0 && row < n) {
        l0 += bc[0];
        l1 += bc[1];
        float m = fmaxf(l0, l1);
        float lse = m + logf(expf(l0 - m) + expf(l1 - m));
        outp[(size_t)row * 2 + 0] = l0 - lse;
        outp[(size_t)row * 2 + 1] = l1 - lse;
    }
}

// ---------------- host ----------------

extern "C" void kernel_launch(void* const* d_in, const int* in_sizes, int n_in,
                              void* d_out, int out_size, void* d_ws, size_t ws_size,
                              hipStream_t stream) {
    const float* x     = (const float*)d_in[0];
    const int*   ei    = (const int*)d_in[1];
    const float* W_in  = (const float*)d_in[2];
    const float* b_in  = (const float*)d_in[3];
    const float* W_l   = (const float*)d_in[4];
    const float* b_l   = (const float*)d_in[5];
    const float* W_r   = (const float*)d_in[6];
    const float* b_r   = (const float*)d_in[7];
    const float* bn_g  = (const float*)d_in[8];
    const float* bn_b  = (const float*)d_in[9];
    const float* bn_m  = (const float*)d_in[10];
    const float* bn_v  = (const float*)d_in[11];
    const float* W_cls = (const float*)d_in[12];
    const float* b_cls = (const float*)d_in[13];
    float* outp = (float*)d_out;

    const int N = in_sizes[0] / IN_DIM;   // 100000
    const int E = in_sizes[1] / 2;        // 1600000

    char* w = (char*)d_ws;
    const size_t HB = (size_t)N * HID * sizeof(ushort);          // 25.6 MB per buffer
    ushort* hA     = (ushort*)(w);
    ushort* hB     = (ushort*)(w + HB);
    ushort* meanb  = (ushort*)(w + 2 * HB);
    int*   row_ptr = (int*)(w + 3 * HB);                         // N+1 ints
    int*   cursor  = (int*)(w + 3 * HB + 400128);
    int*   bsum    = (int*)(w + 3 * HB + 800256);
    int*   esrc    = (int*)(w + 3 * HB + 801280);                // E ints

    const int nbScan = (N + SCAN_ELEMS - 1) / SCAN_ELEMS;

    // --- CSR build ---
    hipMemsetAsync(cursor, 0, (size_t)N * sizeof(int), stream);
    count_deg_kernel<<<(E + 255) / 256, 256, 0, stream>>>(ei, cursor, E);
    scan1_kernel<<<nbScan, SCAN_THREADS, 0, stream>>>(cursor, row_ptr, bsum, N);
    scan2_kernel<<<1, 64, 0, stream>>>(bsum, nbScan);
    scan3_kernel<<<(N + 256) / 256, 256, 0, stream>>>(row_ptr, bsum, N, nbScan);
    hipMemcpyAsync(cursor, row_ptr, (size_t)N * sizeof(int), hipMemcpyDeviceToDevice, stream);
    fill_csr_kernel<<<(E + 255) / 256, 256, 0, stream>>>(ei, cursor, esrc, E);

    // --- input projection (fp32 x -> bf16 h) ---
    input_gemm_mfma<<<640, 256, 0, stream>>>(x, W_in, b_in, hA, N);

    // --- 4 SAGE layers ---
    ushort* hcur = hA;
    ushort* hoth = hB;
    for (int i = 0; i < 4; i++) {
        sage_mean_bf16<<<(N + 3) / 4, 256, 0, stream>>>(hcur, row_ptr, esrc, meanb, N);
        sage_layer_mfma<<<640, 256, 0, stream>>>(hcur, meanb, hoth,
                                                 W_l + (size_t)i * HID * HID, b_l + i * HID,
                                                 W_r + (size_t)i * HID * HID, b_r + i * HID,
                                                 bn_g + i * HID, bn_b + i * HID,
                                                 bn_m + i * HID, bn_v + i * HID, N);
        ushort* tmp = hcur; hcur = hoth; hoth = tmp;
    }

    // --- classifier + log_softmax ---
    classifier_bf16<<<(N + 15) / 16, 256, 0, stream>>>(hcur, W_cls, b_cls, outp, N);
}

// Round 4
// 742.530 us; speedup vs baseline: 3.5830x; 1.1140x over previous
//
#include <hip/hip_runtime.h>

typedef unsigned int uint;
typedef unsigned short ushort;
typedef __attribute__((ext_vector_type(8))) short short8v;  // 8 bf16 bit patterns
typedef __attribute__((ext_vector_type(4))) float f32x4;

#define IN_DIM 256
#define HID 128
#define BN_EPS 1e-5f

__device__ __forceinline__ float bf2f(ushort u) { return __uint_as_float(((uint)u) << 16); }
__device__ __forceinline__ ushort f2bf(float f) {
    uint u = __float_as_uint(f);
    return (ushort)((u + 0x7fffu + ((u >> 16) & 1u)) >> 16);  // RNE
}

// ---------------- CSR build ----------------

__global__ void count_deg_kernel(const int* __restrict__ ei, int* __restrict__ deg, int E) {
    int e = blockIdx.x * blockDim.x + threadIdx.x;
    if (e < E) atomicAdd(&deg[ei[E + e]], 1);
}

#define SCAN_THREADS 256
#define SCAN_ELEMS 1024

__global__ __launch_bounds__(SCAN_THREADS) void scan1_kernel(const int* __restrict__ deg,
                                                             int* __restrict__ outp,
                                                             int* __restrict__ bsum, int n) {
    __shared__ int sdata[SCAN_THREADS];
    int t = threadIdx.x;
    int base = blockIdx.x * SCAN_ELEMS + t * 4;
    int v0 = 0, v1 = 0, v2 = 0, v3 = 0;
    if (base + 0 < n) v0 = deg[base + 0];
    if (base + 1 < n) v1 = deg[base + 1];
    if (base + 2 < n) v2 = deg[base + 2];
    if (base + 3 < n) v3 = deg[base + 3];
    int s = v0 + v1 + v2 + v3;
    sdata[t] = s;
    __syncthreads();
    int val = s;
    for (int off = 1; off < SCAN_THREADS; off <<= 1) {
        int add = (t >= off) ? sdata[t - off] : 0;
        __syncthreads();
        val += add;
        sdata[t] = val;
        __syncthreads();
    }
    int excl = val - s;
    if (base + 0 < n) outp[base + 0] = excl;
    if (base + 1 < n) outp[base + 1] = excl + v0;
    if (base + 2 < n) outp[base + 2] = excl + v0 + v1;
    if (base + 3 < n) outp[base + 3] = excl + v0 + v1 + v2;
    if (t == SCAN_THREADS - 1) bsum[blockIdx.x] = val;
}

__global__ void scan2_kernel(int* bsum, int nb) {
    if (threadIdx.x == 0 && blockIdx.x == 0) {
        int acc = 0;
        for (int i = 0; i < nb; i++) { int v = bsum[i]; bsum[i] = acc; acc += v; }
        bsum[nb] = acc;
    }
}

__global__ void scan3_kernel(int* __restrict__ row_ptr, const int* __restrict__ bsum, int n, int nb) {
    int i = blockIdx.x * blockDim.x + threadIdx.x;
    if (i < n) row_ptr[i] += bsum[i >> 10];
    else if (i == n) row_ptr[n] = bsum[nb];
}

// scattered 4B stores via no-return atomicExch: executed as a 4B op at the
// coherence point instead of a masked 64B line write per store (cuts the
// 105MB write amplification observed in round 3).
__global__ void fill_csr_kernel(const int* __restrict__ ei, int* __restrict__ cursor,
                                int* __restrict__ esrc, int E) {
    int e = blockIdx.x * blockDim.x + threadIdx.x;
    if (e < E) {
        int s = ei[e];
        int d = ei[E + e];
        int pos = atomicAdd(&cursor[d], 1);
        atomicExch(&esrc[pos], s);
    }
}

// ---------------- Aggregation: mean over in-neighbors (bf16 rows) ----------------
// one wave per node; lane owns 2 cols (one dword = 2 bf16); per edge = one
// 256B fully-coalesced wave load. 4 edges in flight. fp32 accumulate, bf16 out.

__global__ __launch_bounds__(256) void sage_mean_bf16(const ushort* __restrict__ h,
                                                      const int* __restrict__ row_ptr,
                                                      const int* __restrict__ esrc,
                                                      ushort* __restrict__ meanb, int n) {
    int node = blockIdx.x * 4 + (threadIdx.x >> 6);
    if (node >= n) return;
    int lane = threadIdx.x & 63;
    int start = row_ptr[node];
    int end = row_ptr[node + 1];
    float ax = 0.f, ay = 0.f;
    int j = start;
    for (; j + 3 < end; j += 4) {
        int s0 = esrc[j];
        int s1 = esrc[j + 1];
        int s2 = esrc[j + 2];
        int s3 = esrc[j + 3];
        uint v0 = *(const uint*)(h + (size_t)s0 * HID + lane * 2);
        uint v1 = *(const uint*)(h + (size_t)s1 * HID + lane * 2);
        uint v2 = *(const uint*)(h + (size_t)s2 * HID + lane * 2);
        uint v3 = *(const uint*)(h + (size_t)s3 * HID + lane * 2);
        ax += bf2f((ushort)(v0 & 0xffffu)) + bf2f((ushort)(v1 & 0xffffu))
            + bf2f((ushort)(v2 & 0xffffu)) + bf2f((ushort)(v3 & 0xffffu));
        ay += bf2f((ushort)(v0 >> 16)) + bf2f((ushort)(v1 >> 16))
            + bf2f((ushort)(v2 >> 16)) + bf2f((ushort)(v3 >> 16));
    }
    for (; j < end; ++j) {
        int s0 = esrc[j];
        uint v0 = *(const uint*)(h + (size_t)s0 * HID + lane * 2);
        ax += bf2f((ushort)(v0 & 0xffffu));
        ay += bf2f((ushort)(v0 >> 16));
    }
    int deg = end - start;
    float inv = 1.0f / (float)(deg > 1 ? deg : 1);
    uint o = (uint)f2bf(ax * inv) | (((uint)f2bf(ay * inv)) << 16);
    *(uint*)(meanb + (size_t)node * HID + lane * 2) = o;
}

// ---------------- Input GEMM: h = relu(x @ W_in + b_in), MFMA ----------------

__global__ __launch_bounds__(256) void input_gemm_mfma(const float* __restrict__ x,
                                                       const float* __restrict__ W,
                                                       const float* __restrict__ b,
                                                       ushort* __restrict__ hout, int n) {
    int t = threadIdx.x;
    int l = t & 63;
    int wv = t >> 6;
    int colbase = wv * 32;
    int lr = l & 15;   // A-row / B,D-col within tile
    int grp = l >> 4;  // k-group
    int ko = grp * 8;

    short8v Bf[8][2];
    #pragma unroll
    for (int ks = 0; ks < 8; ks++) {
        #pragma unroll
        for (int nt = 0; nt < 2; nt++) {
            int c = colbase + nt * 16 + lr;
            short8v f;
            #pragma unroll
            for (int jj = 0; jj < 8; jj++)
                f[jj] = (short)f2bf(W[(size_t)(ks * 32 + ko + jj) * HID + c]);
            Bf[ks][nt] = f;
        }
    }
    float bias0 = b[colbase + lr];
    float bias1 = b[colbase + 16 + lr];

    int ntiles = (n + 15) >> 4;
    for (int tile = blockIdx.x; tile < ntiles; tile += gridDim.x) {
        int row0 = tile * 16;
        int arow = row0 + lr;
        const float* xr = x + (size_t)arow * IN_DIM + ko;
        short8v Af[8];
        if (arow < n) {
            #pragma unroll
            for (int ks = 0; ks < 8; ks++) {
                float4 p = *(const float4*)(xr + ks * 32);
                float4 q = *(const float4*)(xr + ks * 32 + 4);
                short8v a;
                a[0] = (short)f2bf(p.x); a[1] = (short)f2bf(p.y);
                a[2] = (short)f2bf(p.z); a[3] = (short)f2bf(p.w);
                a[4] = (short)f2bf(q.x); a[5] = (short)f2bf(q.y);
                a[6] = (short)f2bf(q.z); a[7] = (short)f2bf(q.w);
                Af[ks] = a;
            }
        } else {
            #pragma unroll
            for (int ks = 0; ks < 8; ks++) {
                short8v a = {0, 0, 0, 0, 0, 0, 0, 0};
                Af[ks] = a;
            }
        }
        f32x4 acc0 = {0.f, 0.f, 0.f, 0.f};
        f32x4 acc1 = {0.f, 0.f, 0.f, 0.f};
        #pragma unroll
        for (int ks = 0; ks < 8; ks++) {
            acc0 = __builtin_amdgcn_mfma_f32_16x16x32_bf16(Af[ks], Bf[ks][0], acc0, 0, 0, 0);
            acc1 = __builtin_amdgcn_mfma_f32_16x16x32_bf16(Af[ks], Bf[ks][1], acc1, 0, 0, 0);
        }
        int rbase = row0 + grp * 4;
        #pragma unroll
        for (int r = 0; r < 4; r++) {
            int rowd = rbase + r;
            if (rowd < n) {
                float z0 = acc0[r] + bias0; z0 = z0 > 0.f ? z0 : 0.f;
                float z1 = acc1[r] + bias1; z1 = z1 > 0.f ? z1 : 0.f;
                hout[(size_t)rowd * HID + colbase + lr] = f2bf(z0);
                hout[(size_t)rowd * HID + colbase + 16 + lr] = f2bf(z1);
            }
        }
    }
}

// ---------------- Fused SAGE layer, MFMA ----------------
// hout = relu(BN(mean@Wl + h@Wr + biases)) + h ; K=256 over concat[mean|h].

__global__ __launch_bounds__(256) void sage_layer_mfma(const ushort* __restrict__ h,
                                                       const ushort* __restrict__ mh,
                                                       ushort* __restrict__ hout,
                                                       const float* __restrict__ Wl,
                                                       const float* __restrict__ bl,
                                                       const float* __restrict__ Wr,
                                                       const float* __restrict__ br,
                                                       const float* __restrict__ gamma,
                                                       const float* __restrict__ beta,
                                                       const float* __restrict__ bmean,
                                                       const float* __restrict__ bvar,
                                                       int n) {
    int t = threadIdx.x;
    int l = t & 63;
    int wv = t >> 6;
    int colbase = wv * 32;
    int lr = l & 15;
    int grp = l >> 4;
    int ko = grp * 8;

    short8v Bf[8][2];
    #pragma unroll
    for (int ks = 0; ks < 8; ks++) {
        const float* Wsrc = (ks < 4) ? Wl : Wr;
        int kb = (ks < 4) ? ks * 32 : (ks - 4) * 32;
        #pragma unroll
        for (int nt = 0; nt < 2; nt++) {
            int c = colbase + nt * 16 + lr;
            short8v f;
            #pragma unroll
            for (int jj = 0; jj < 8; jj++)
                f[jj] = (short)f2bf(Wsrc[(size_t)(kb + ko + jj) * HID + c]);
            Bf[ks][nt] = f;
        }
    }
    int c0 = colbase + lr;
    int c1 = c0 + 16;
    float scale0 = gamma[c0] * rsqrtf(bvar[c0] + BN_EPS);
    float scale1 = gamma[c1] * rsqrtf(bvar[c1] + BN_EPS);
    float shift0 = beta[c0] + (bl[c0] + br[c0] - bmean[c0]) * scale0;
    float shift1 = beta[c1] + (bl[c1] + br[c1] - bmean[c1]) * scale1;

    int ntiles = (n + 15) >> 4;
    for (int tile = blockIdx.x; tile < ntiles; tile += gridDim.x) {
        int row0 = tile * 16;
        int arow = row0 + lr;
        short8v Af[8];
        if (arow < n) {
            const ushort* mrow = mh + (size_t)arow * HID + ko;
            const ushort* hrow = h + (size_t)arow * HID + ko;
            #pragma unroll
            for (int ks = 0; ks < 4; ks++) Af[ks] = *(const short8v*)(mrow + ks * 32);
            #pragma unroll
            for (int ks = 4; ks < 8; ks++) Af[ks] = *(const short8v*)(hrow + (ks - 4) * 32);
        } else {
            #pragma unroll
            for (int ks = 0; ks < 8; ks++) {
                short8v a = {0, 0, 0, 0, 0, 0, 0, 0};
                Af[ks] = a;
            }
        }
        f32x4 acc0 = {0.f, 0.f, 0.f, 0.f};
        f32x4 acc1 = {0.f, 0.f, 0.f, 0.f};
        #pragma unroll
        for (int ks = 0; ks < 8; ks++) {
            acc0 = __builtin_amdgcn_mfma_f32_16x16x32_bf16(Af[ks], Bf[ks][0], acc0, 0, 0, 0);
            acc1 = __builtin_amdgcn_mfma_f32_16x16x32_bf16(Af[ks], Bf[ks][1], acc1, 0, 0, 0);
        }
        int rbase = row0 + grp * 4;
        #pragma unroll
        for (int r = 0; r < 4; r++) {
            int rowd = rbase + r;
            if (rowd < n) {
                float z0 = acc0[r] * scale0 + shift0; z0 = z0 > 0.f ? z0 : 0.f;
                float z1 = acc1[r] * scale1 + shift1; z1 = z1 > 0.f ? z1 : 0.f;
                z0 += bf2f(h[(size_t)rowd * HID + c0]);
                z1 += bf2f(h[(size_t)rowd * HID + c1]);
                hout[(size_t)rowd * HID + c0] = f2bf(z0);
                hout[(size_t)rowd * HID + c1] = f2bf(z1);
            }
        }
    }
}

// ---------------- Classifier + log_softmax (bf16 h) ----------------

__global__ __launch_bounds__(256) void classifier_bf16(const ushort* __restrict__ h,
                                                       const float* __restrict__ Wc,
                                                       const float* __restrict__ bc,
                                                       float* __restrict__ outp, int n) {
    __shared__ float Wcs[HID * 2];
    int t = threadIdx.x;
    if (t < 64) *(float4*)&Wcs[t * 4] = *(const float4*)&Wc[t * 4];
    __syncthreads();
    int rowInBlk = t >> 4;
    int sub = t & 15;
    int row = blockIdx.x * 16 + rowInBlk;
    float l0 = 0.f, l1 = 0.f;
    if (row < n) {
        const ushort* hr = h + (size_t)row * HID + sub * 8;
        uint4 v = *(const uint4*)hr;
        float e0 = bf2f((ushort)(v.x & 0xffffu)), e1 = bf2f((ushort)(v.x >> 16));
        float e2 = bf2f((ushort)(v.y & 0xffffu)), e3 = bf2f((ushort)(v.y >> 16));
        float e4 = bf2f((ushort)(v.z & 0xffffu)), e5 = bf2f((ushort)(v.z >> 16));
        float e6 = bf2f((ushort)(v.w & 0xffffu)), e7 = bf2f((ushort)(v.w >> 16));
        int k0 = sub * 8;
        l0 += e0 * Wcs[(k0 + 0) * 2] + e1 * Wcs[(k0 + 1) * 2] + e2 * Wcs[(k0 + 2) * 2] + e3 * Wcs[(k0 + 3) * 2];
        l0 += e4 * Wcs[(k0 + 4) * 2] + e5 * Wcs[(k0 + 5) * 2] + e6 * Wcs[(k0 + 6) * 2] + e7 * Wcs[(k0 + 7) * 2];
        l1 += e0 * Wcs[(k0 + 0) * 2 + 1] + e1 * Wcs[(k0 + 1) * 2 + 1] + e2 * Wcs[(k0 + 2) * 2 + 1] + e3 * Wcs[(k0 + 3) * 2 + 1];
        l1 += e4 * Wcs[(k0 + 4) * 2 + 1] + e5 * Wcs[(k0 + 5) * 2 + 1] + e6 * Wcs[(k0 + 6) * 2 + 1] + e7 * Wcs[(k0 + 7) * 2 + 1];
    }
    #pragma unroll
    for (int off = 1; off < 16; off <<= 1) {
        l0 += __shfl_xor(l0, off);
        l1 += __shfl_xor(l1, off);
    }
    if (sub == 0 && row < n) {
        l0 += bc[0];
        l1 += bc[1];
        float m = fmaxf(l0, l1);
        float lse = m + logf(expf(l0 - m) + expf(l1 - m));
        outp[(size_t)row * 2 + 0] = l0 - lse;
        outp[(size_t)row * 2 + 1] = l1 - lse;
    }
}

// ---------------- host ----------------

extern "C" void kernel_launch(void* const* d_in, const int* in_sizes, int n_in,
                              void* d_out, int out_size, void* d_ws, size_t ws_size,
                              hipStream_t stream) {
    const float* x     = (const float*)d_in[0];
    const int*   ei    = (const int*)d_in[1];
    const float* W_in  = (const float*)d_in[2];
    const float* b_in  = (const float*)d_in[3];
    const float* W_l   = (const float*)d_in[4];
    const float* b_l   = (const float*)d_in[5];
    const float* W_r   = (const float*)d_in[6];
    const float* b_r   = (const float*)d_in[7];
    const float* bn_g  = (const float*)d_in[8];
    const float* bn_b  = (const float*)d_in[9];
    const float* bn_m  = (const float*)d_in[10];
    const float* bn_v  = (const float*)d_in[11];
    const float* W_cls = (const float*)d_in[12];
    const float* b_cls = (const float*)d_in[13];
    float* outp = (float*)d_out;

    const int N = in_sizes[0] / IN_DIM;   // 100000
    const int E = in_sizes[1] / 2;        // 1600000

    char* w = (char*)d_ws;
    const size_t HB = (size_t)N * HID * sizeof(ushort);          // 25.6 MB per buffer
    ushort* hA     = (ushort*)(w);
    ushort* hB     = (ushort*)(w + HB);
    ushort* meanb  = (ushort*)(w + 2 * HB);
    int*   row_ptr = (int*)(w + 3 * HB);                         // N+1 ints
    int*   cursor  = (int*)(w + 3 * HB + 400128);
    int*   bsum    = (int*)(w + 3 * HB + 800256);
    int*   esrc    = (int*)(w + 3 * HB + 801280);                // E ints

    const int nbScan = (N + SCAN_ELEMS - 1) / SCAN_ELEMS;

    // --- CSR build ---
    hipMemsetAsync(cursor, 0, (size_t)N * sizeof(int), stream);
    count_deg_kernel<<<(E + 255) / 256, 256, 0, stream>>>(ei, cursor, E);
    scan1_kernel<<<nbScan, SCAN_THREADS, 0, stream>>>(cursor, row_ptr, bsum, N);
    scan2_kernel<<<1, 64, 0, stream>>>(bsum, nbScan);
    scan3_kernel<<<(N + 256) / 256, 256, 0, stream>>>(row_ptr, bsum, N, nbScan);
    hipMemcpyAsync(cursor, row_ptr, (size_t)N * sizeof(int), hipMemcpyDeviceToDevice, stream);
    fill_csr_kernel<<<(E + 255) / 256, 256, 0, stream>>>(ei, cursor, esrc, E);

    // --- input projection (fp32 x -> bf16 h) ---
    input_gemm_mfma<<<640, 256, 0, stream>>>(x, W_in, b_in, hA, N);

    // --- 4 SAGE layers ---
    ushort* hcur = hA;
    ushort* hoth = hB;
    for (int i = 0; i < 4; i++) {
        sage_mean_bf16<<<(N + 3) / 4, 256, 0, stream>>>(hcur, row_ptr, esrc, meanb, N);
        sage_layer_mfma<<<640, 256, 0, stream>>>(hcur, meanb, hoth,
                                                 W_l + (size_t)i * HID * HID, b_l + i * HID,
                                                 W_r + (size_t)i * HID * HID, b_r + i * HID,
                                                 bn_g + i * HID, bn_b + i * HID,
                                                 bn_m + i * HID, bn_v + i * HID, N);
        ushort* tmp = hcur; hcur = hoth; hoth = tmp;
    }

    // --- classifier + log_softmax ---
    classifier_bf16<<<(N + 15) / 16, 256, 0, stream>>>(hcur, W_cls, b_cls, outp, N);
}

// Round 5
// 678.436 us; speedup vs baseline: 3.9216x; 1.0945x over previous
//
#include <hip/hip_runtime.h>

typedef unsigned int uint;
typedef unsigned short ushort;
typedef __attribute__((ext_vector_type(8))) short short8v;  // 8 bf16 bit patterns
typedef __attribute__((ext_vector_type(4))) float f32x4;

#define IN_DIM 256
#define HID 128
#define BN_EPS 1e-5f
#define NSHARD 8

__device__ __forceinline__ float bf2f(ushort u) { return __uint_as_float(((uint)u) << 16); }
__device__ __forceinline__ ushort f2bf(float f) {
    uint u = __float_as_uint(f);
    return (ushort)((u + 0x7fffu + ((u >> 16) & 1u)) >> 16);  // RNE
}

// ---------------- CSR build ----------------

__global__ void count_deg_kernel(const int* __restrict__ ei, int* __restrict__ deg, int E) {
    int e = blockIdx.x * blockDim.x + threadIdx.x;
    if (e < E) atomicAdd(&deg[ei[E + e]], 1);
}

#define SCAN_THREADS 256
#define SCAN_ELEMS 1024

__global__ __launch_bounds__(SCAN_THREADS) void scan1_kernel(const int* __restrict__ deg,
                                                             int* __restrict__ outp,
                                                             int* __restrict__ bsum, int n) {
    __shared__ int sdata[SCAN_THREADS];
    int t = threadIdx.x;
    int base = blockIdx.x * SCAN_ELEMS + t * 4;
    int v0 = 0, v1 = 0, v2 = 0, v3 = 0;
    if (base + 0 < n) v0 = deg[base + 0];
    if (base + 1 < n) v1 = deg[base + 1];
    if (base + 2 < n) v2 = deg[base + 2];
    if (base + 3 < n) v3 = deg[base + 3];
    int s = v0 + v1 + v2 + v3;
    sdata[t] = s;
    __syncthreads();
    int val = s;
    for (int off = 1; off < SCAN_THREADS; off <<= 1) {
        int add = (t >= off) ? sdata[t - off] : 0;
        __syncthreads();
        val += add;
        sdata[t] = val;
        __syncthreads();
    }
    int excl = val - s;
    if (base + 0 < n) outp[base + 0] = excl;
    if (base + 1 < n) outp[base + 1] = excl + v0;
    if (base + 2 < n) outp[base + 2] = excl + v0 + v1;
    if (base + 3 < n) outp[base + 3] = excl + v0 + v1 + v2;
    if (t == SCAN_THREADS - 1) bsum[blockIdx.x] = val;
}

__global__ void scan2_kernel(int* bsum, int nb) {
    if (threadIdx.x == 0 && blockIdx.x == 0) {
        int acc = 0;
        for (int i = 0; i < nb; i++) { int v = bsum[i]; bsum[i] = acc; acc += v; }
        bsum[nb] = acc;
    }
}

__global__ void scan3_kernel(int* __restrict__ row_ptr, const int* __restrict__ bsum, int n, int nb) {
    int i = blockIdx.x * blockDim.x + threadIdx.x;
    if (i < n) row_ptr[i] += bsum[i >> 10];
    else if (i == n) row_ptr[n] = bsum[nb];
}

// XCD-sharded CSR fill. shard = blockIdx.x & 7 rides the round-robin
// blockIdx->XCD mapping: each contiguous dst slice (and its ~800KB esrc
// slice) is written by ONE XCD only -> writes merge in that XCD's L2 and
// evict as full lines (vs round-3/4's 1 masked line per 4B write, 102MB).
// Correctness does NOT depend on the mapping: every shard is scanned by
// its 256-workgroup team regardless of placement.
__global__ __launch_bounds__(256) void fill_csr_sharded(const int* __restrict__ ei,
                                                        int* __restrict__ cursor,
                                                        int* __restrict__ esrc,
                                                        int E, int shardSize) {
    int s = blockIdx.x & (NSHARD - 1);
    int rank = blockIdx.x >> 3;           // rank within shard team
    int nteam = gridDim.x >> 3;           // team size
    int lo = s * shardSize;
    int hi = lo + shardSize;
    int stride = nteam * blockDim.x;
    for (int e = rank * blockDim.x + threadIdx.x; e < E; e += stride) {
        int d = ei[E + e];
        if (d >= lo && d < hi) {
            int pos = atomicAdd(&cursor[d], 1);
            esrc[pos] = ei[e];
        }
    }
}

// ---------------- Aggregation: mean over in-neighbors (bf16 rows) ----------------
// one wave per node; lane owns 2 cols (one dword = 2 bf16); per edge = one
// 256B fully-coalesced wave load. 4 edges in flight. fp32 accumulate, bf16 out.

__global__ __launch_bounds__(256) void sage_mean_bf16(const ushort* __restrict__ h,
                                                      const int* __restrict__ row_ptr,
                                                      const int* __restrict__ esrc,
                                                      ushort* __restrict__ meanb, int n) {
    int node = blockIdx.x * 4 + (threadIdx.x >> 6);
    if (node >= n) return;
    int lane = threadIdx.x & 63;
    int start = row_ptr[node];
    int end = row_ptr[node + 1];
    float ax = 0.f, ay = 0.f;
    int j = start;
    for (; j + 3 < end; j += 4) {
        int s0 = esrc[j];
        int s1 = esrc[j + 1];
        int s2 = esrc[j + 2];
        int s3 = esrc[j + 3];
        uint v0 = *(const uint*)(h + (size_t)s0 * HID + lane * 2);
        uint v1 = *(const uint*)(h + (size_t)s1 * HID + lane * 2);
        uint v2 = *(const uint*)(h + (size_t)s2 * HID + lane * 2);
        uint v3 = *(const uint*)(h + (size_t)s3 * HID + lane * 2);
        ax += bf2f((ushort)(v0 & 0xffffu)) + bf2f((ushort)(v1 & 0xffffu))
            + bf2f((ushort)(v2 & 0xffffu)) + bf2f((ushort)(v3 & 0xffffu));
        ay += bf2f((ushort)(v0 >> 16)) + bf2f((ushort)(v1 >> 16))
            + bf2f((ushort)(v2 >> 16)) + bf2f((ushort)(v3 >> 16));
    }
    for (; j < end; ++j) {
        int s0 = esrc[j];
        uint v0 = *(const uint*)(h + (size_t)s0 * HID + lane * 2);
        ax += bf2f((ushort)(v0 & 0xffffu));
        ay += bf2f((ushort)(v0 >> 16));
    }
    int deg = end - start;
    float inv = 1.0f / (float)(deg > 1 ? deg : 1);
    uint o = (uint)f2bf(ax * inv) | (((uint)f2bf(ay * inv)) << 16);
    *(uint*)(meanb + (size_t)node * HID + lane * 2) = o;
}

// ---------------- Input GEMM: h = relu(x @ W_in + b_in), MFMA ----------------

__global__ __launch_bounds__(256) void input_gemm_mfma(const float* __restrict__ x,
                                                       const float* __restrict__ W,
                                                       const float* __restrict__ b,
                                                       ushort* __restrict__ hout, int n) {
    int t = threadIdx.x;
    int l = t & 63;
    int wv = t >> 6;
    int colbase = wv * 32;
    int lr = l & 15;   // A-row / B,D-col within tile
    int grp = l >> 4;  // k-group
    int ko = grp * 8;

    short8v Bf[8][2];
    #pragma unroll
    for (int ks = 0; ks < 8; ks++) {
        #pragma unroll
        for (int nt = 0; nt < 2; nt++) {
            int c = colbase + nt * 16 + lr;
            short8v f;
            #pragma unroll
            for (int jj = 0; jj < 8; jj++)
                f[jj] = (short)f2bf(W[(size_t)(ks * 32 + ko + jj) * HID + c]);
            Bf[ks][nt] = f;
        }
    }
    float bias0 = b[colbase + lr];
    float bias1 = b[colbase + 16 + lr];

    int ntiles = (n + 15) >> 4;
    for (int tile = blockIdx.x; tile < ntiles; tile += gridDim.x) {
        int row0 = tile * 16;
        int arow = row0 + lr;
        const float* xr = x + (size_t)arow * IN_DIM + ko;
        short8v Af[8];
        if (arow < n) {
            #pragma unroll
            for (int ks = 0; ks < 8; ks++) {
                float4 p = *(const float4*)(xr + ks * 32);
                float4 q = *(const float4*)(xr + ks * 32 + 4);
                short8v a;
                a[0] = (short)f2bf(p.x); a[1] = (short)f2bf(p.y);
                a[2] = (short)f2bf(p.z); a[3] = (short)f2bf(p.w);
                a[4] = (short)f2bf(q.x); a[5] = (short)f2bf(q.y);
                a[6] = (short)f2bf(q.z); a[7] = (short)f2bf(q.w);
                Af[ks] = a;
            }
        } else {
            #pragma unroll
            for (int ks = 0; ks < 8; ks++) {
                short8v a = {0, 0, 0, 0, 0, 0, 0, 0};
                Af[ks] = a;
            }
        }
        f32x4 acc0 = {0.f, 0.f, 0.f, 0.f};
        f32x4 acc1 = {0.f, 0.f, 0.f, 0.f};
        #pragma unroll
        for (int ks = 0; ks < 8; ks++) {
            acc0 = __builtin_amdgcn_mfma_f32_16x16x32_bf16(Af[ks], Bf[ks][0], acc0, 0, 0, 0);
            acc1 = __builtin_amdgcn_mfma_f32_16x16x32_bf16(Af[ks], Bf[ks][1], acc1, 0, 0, 0);
        }
        int rbase = row0 + grp * 4;
        #pragma unroll
        for (int r = 0; r < 4; r++) {
            int rowd = rbase + r;
            if (rowd < n) {
                float z0 = acc0[r] + bias0; z0 = z0 > 0.f ? z0 : 0.f;
                float z1 = acc1[r] + bias1; z1 = z1 > 0.f ? z1 : 0.f;
                hout[(size_t)rowd * HID + colbase + lr] = f2bf(z0);
                hout[(size_t)rowd * HID + colbase + 16 + lr] = f2bf(z1);
            }
        }
    }
}

// ---------------- Fused SAGE layer, MFMA ----------------
// hout = relu(BN(mean@Wl + h@Wr + biases)) + h ; K=256 over concat[mean|h].

__global__ __launch_bounds__(256) void sage_layer_mfma(const ushort* __restrict__ h,
                                                       const ushort* __restrict__ mh,
                                                       ushort* __restrict__ hout,
                                                       const float* __restrict__ Wl,
                                                       const float* __restrict__ bl,
                                                       const float* __restrict__ Wr,
                                                       const float* __restrict__ br,
                                                       const float* __restrict__ gamma,
                                                       const float* __restrict__ beta,
                                                       const float* __restrict__ bmean,
                                                       const float* __restrict__ bvar,
                                                       int n) {
    int t = threadIdx.x;
    int l = t & 63;
    int wv = t >> 6;
    int colbase = wv * 32;
    int lr = l & 15;
    int grp = l >> 4;
    int ko = grp * 8;

    short8v Bf[8][2];
    #pragma unroll
    for (int ks = 0; ks < 8; ks++) {
        const float* Wsrc = (ks < 4) ? Wl : Wr;
        int kb = (ks < 4) ? ks * 32 : (ks - 4) * 32;
        #pragma unroll
        for (int nt = 0; nt < 2; nt++) {
            int c = colbase + nt * 16 + lr;
            short8v f;
            #pragma unroll
            for (int jj = 0; jj < 8; jj++)
                f[jj] = (short)f2bf(Wsrc[(size_t)(kb + ko + jj) * HID + c]);
            Bf[ks][nt] = f;
        }
    }
    int c0 = colbase + lr;
    int c1 = c0 + 16;
    float scale0 = gamma[c0] * rsqrtf(bvar[c0] + BN_EPS);
    float scale1 = gamma[c1] * rsqrtf(bvar[c1] + BN_EPS);
    float shift0 = beta[c0] + (bl[c0] + br[c0] - bmean[c0]) * scale0;
    float shift1 = beta[c1] + (bl[c1] + br[c1] - bmean[c1]) * scale1;

    int ntiles = (n + 15) >> 4;
    for (int tile = blockIdx.x; tile < ntiles; tile += gridDim.x) {
        int row0 = tile * 16;
        int arow = row0 + lr;
        short8v Af[8];
        if (arow < n) {
            const ushort* mrow = mh + (size_t)arow * HID + ko;
            const ushort* hrow = h + (size_t)arow * HID + ko;
            #pragma unroll
            for (int ks = 0; ks < 4; ks++) Af[ks] = *(const short8v*)(mrow + ks * 32);
            #pragma unroll
            for (int ks = 4; ks < 8; ks++) Af[ks] = *(const short8v*)(hrow + (ks - 4) * 32);
        } else {
            #pragma unroll
            for (int ks = 0; ks < 8; ks++) {
                short8v a = {0, 0, 0, 0, 0, 0, 0, 0};
                Af[ks] = a;
            }
        }
        f32x4 acc0 = {0.f, 0.f, 0.f, 0.f};
        f32x4 acc1 = {0.f, 0.f, 0.f, 0.f};
        #pragma unroll
        for (int ks = 0; ks < 8; ks++) {
            acc0 = __builtin_amdgcn_mfma_f32_16x16x32_bf16(Af[ks], Bf[ks][0], acc0, 0, 0, 0);
            acc1 = __builtin_amdgcn_mfma_f32_16x16x32_bf16(Af[ks], Bf[ks][1], acc1, 0, 0, 0);
        }
        int rbase = row0 + grp * 4;
        #pragma unroll
        for (int r = 0; r < 4; r++) {
            int rowd = rbase + r;
            if (rowd < n) {
                float z0 = acc0[r] * scale0 + shift0; z0 = z0 > 0.f ? z0 : 0.f;
                float z1 = acc1[r] * scale1 + shift1; z1 = z1 > 0.f ? z1 : 0.f;
                z0 += bf2f(h[(size_t)rowd * HID + c0]);
                z1 += bf2f(h[(size_t)rowd * HID + c1]);
                hout[(size_t)rowd * HID + c0] = f2bf(z0);
                hout[(size_t)rowd * HID + c1] = f2bf(z1);
            }
        }
    }
}

// ---------------- Classifier + log_softmax (bf16 h) ----------------

__global__ __launch_bounds__(256) void classifier_bf16(const ushort* __restrict__ h,
                                                       const float* __restrict__ Wc,
                                                       const float* __restrict__ bc,
                                                       float* __restrict__ outp, int n) {
    __shared__ float Wcs[HID * 2];
    int t = threadIdx.x;
    if (t < 64) *(float4*)&Wcs[t * 4] = *(const float4*)&Wc[t * 4];
    __syncthreads();
    int rowInBlk = t >> 4;
    int sub = t & 15;
    int row = blockIdx.x * 16 + rowInBlk;
    float l0 = 0.f, l1 = 0.f;
    if (row < n) {
        const ushort* hr = h + (size_t)row * HID + sub * 8;
        uint4 v = *(const uint4*)hr;
        float e0 = bf2f((ushort)(v.x & 0xffffu)), e1 = bf2f((ushort)(v.x >> 16));
        float e2 = bf2f((ushort)(v.y & 0xffffu)), e3 = bf2f((ushort)(v.y >> 16));
        float e4 = bf2f((ushort)(v.z & 0xffffu)), e5 = bf2f((ushort)(v.z >> 16));
        float e6 = bf2f((ushort)(v.w & 0xffffu)), e7 = bf2f((ushort)(v.w >> 16));
        int k0 = sub * 8;
        l0 += e0 * Wcs[(k0 + 0) * 2] + e1 * Wcs[(k0 + 1) * 2] + e2 * Wcs[(k0 + 2) * 2] + e3 * Wcs[(k0 + 3) * 2];
        l0 += e4 * Wcs[(k0 + 4) * 2] + e5 * Wcs[(k0 + 5) * 2] + e6 * Wcs[(k0 + 6) * 2] + e7 * Wcs[(k0 + 7) * 2];
        l1 += e0 * Wcs[(k0 + 0) * 2 + 1] + e1 * Wcs[(k0 + 1) * 2 + 1] + e2 * Wcs[(k0 + 2) * 2 + 1] + e3 * Wcs[(k0 + 3) * 2 + 1];
        l1 += e4 * Wcs[(k0 + 4) * 2 + 1] + e5 * Wcs[(k0 + 5) * 2 + 1] + e6 * Wcs[(k0 + 6) * 2 + 1] + e7 * Wcs[(k0 + 7) * 2 + 1];
    }
    #pragma unroll
    for (int off = 1; off < 16; off <<= 1) {
        l0 += __shfl_xor(l0, off);
        l1 += __shfl_xor(l1, off);
    }
    if (sub == 0 && row < n) {
        l0 += bc[0];
        l1 += bc[1];
        float m = fmaxf(l0, l1);
        float lse = m + logf(expf(l0 - m) + expf(l1 - m));
        outp[(size_t)row * 2 + 0] = l0 - lse;
        outp[(size_t)row * 2 + 1] = l1 - lse;
    }
}

// ---------------- host ----------------

extern "C" void kernel_launch(void* const* d_in, const int* in_sizes, int n_in,
                              void* d_out, int out_size, void* d_ws, size_t ws_size,
                              hipStream_t stream) {
    const float* x     = (const float*)d_in[0];
    const int*   ei    = (const int*)d_in[1];
    const float* W_in  = (const float*)d_in[2];
    const float* b_in  = (const float*)d_in[3];
    const float* W_l   = (const float*)d_in[4];
    const float* b_l   = (const float*)d_in[5];
    const float* W_r   = (const float*)d_in[6];
    const float* b_r   = (const float*)d_in[7];
    const float* bn_g  = (const float*)d_in[8];
    const float* bn_b  = (const float*)d_in[9];
    const float* bn_m  = (const float*)d_in[10];
    const float* bn_v  = (const float*)d_in[11];
    const float* W_cls = (const float*)d_in[12];
    const float* b_cls = (const float*)d_in[13];
    float* outp = (float*)d_out;

    const int N = in_sizes[0] / IN_DIM;   // 100000
    const int E = in_sizes[1] / 2;        // 1600000

    char* w = (char*)d_ws;
    const size_t HB = (size_t)N * HID * sizeof(ushort);          // 25.6 MB per buffer
    ushort* hA     = (ushort*)(w);
    ushort* hB     = (ushort*)(w + HB);
    ushort* meanb  = (ushort*)(w + 2 * HB);
    int*   row_ptr = (int*)(w + 3 * HB);                         // N+1 ints
    int*   cursor  = (int*)(w + 3 * HB + 400128);
    int*   bsum    = (int*)(w + 3 * HB + 800256);
    int*   esrc    = (int*)(w + 3 * HB + 801280);                // E ints

    const int nbScan = (N + SCAN_ELEMS - 1) / SCAN_ELEMS;
    const int shardSize = (N + NSHARD - 1) / NSHARD;             // 12500

    // --- CSR build ---
    hipMemsetAsync(cursor, 0, (size_t)N * sizeof(int), stream);
    count_deg_kernel<<<(E + 255) / 256, 256, 0, stream>>>(ei, cursor, E);
    scan1_kernel<<<nbScan, SCAN_THREADS, 0, stream>>>(cursor, row_ptr, bsum, N);
    scan2_kernel<<<1, 64, 0, stream>>>(bsum, nbScan);
    scan3_kernel<<<(N + 256) / 256, 256, 0, stream>>>(row_ptr, bsum, N, nbScan);
    hipMemcpyAsync(cursor, row_ptr, (size_t)N * sizeof(int), hipMemcpyDeviceToDevice, stream);
    fill_csr_sharded<<<2048, 256, 0, stream>>>(ei, cursor, esrc, E, shardSize);

    // --- input projection (fp32 x -> bf16 h) ---
    input_gemm_mfma<<<640, 256, 0, stream>>>(x, W_in, b_in, hA, N);

    // --- 4 SAGE layers ---
    ushort* hcur = hA;
    ushort* hoth = hB;
    for (int i = 0; i < 4; i++) {
        sage_mean_bf16<<<(N + 3) / 4, 256, 0, stream>>>(hcur, row_ptr, esrc, meanb, N);
        sage_layer_mfma<<<640, 256, 0, stream>>>(hcur, meanb, hoth,
                                                 W_l + (size_t)i * HID * HID, b_l + i * HID,
                                                 W_r + (size_t)i * HID * HID, b_r + i * HID,
                                                 bn_g + i * HID, bn_b + i * HID,
                                                 bn_m + i * HID, bn_v + i * HID, N);
        ushort* tmp = hcur; hcur = hoth; hoth = tmp;
    }

    // --- classifier + log_softmax ---
    classifier_bf16<<<(N + 15) / 16, 256, 0, stream>>>(hcur, W_cls, b_cls, outp, N);
}